// Round 1
// baseline (373.820 us; speedup 1.0000x reference)
//
#include <hip/hip_runtime.h>

typedef __attribute__((ext_vector_type(8))) short short8;
typedef __attribute__((ext_vector_type(4))) short short4v;
typedef __attribute__((ext_vector_type(4))) float float4a;
typedef __attribute__((ext_vector_type(16))) float float16a;
typedef __attribute__((ext_vector_type(4))) unsigned int uint4v;

#define MFMA16(a, b, c) __builtin_amdgcn_mfma_f32_16x16x32_bf16(a, b, c, 0, 0, 0)
#define MFMA32(a, b, c) __builtin_amdgcn_mfma_f32_32x32x16_bf16(a, b, c, 0, 0, 0)

static __device__ __forceinline__ short f2bf(float f) {
  unsigned u = __builtin_bit_cast(unsigned, f);
  u += 0x7fff + ((u >> 16) & 1);   // RNE
  return (short)(u >> 16);
}
static __device__ __forceinline__ float bf2f(short s) {
  unsigned u = ((unsigned)(unsigned short)s) << 16;
  return __builtin_bit_cast(float, u);
}

// async global->LDS, 16 B per lane. LDS dest = wave-uniform base + lane*16.
static __device__ __forceinline__ void gl2lds(const short* g, short* l) {
  __builtin_amdgcn_global_load_lds(
      (const __attribute__((address_space(1))) void*)g,
      (__attribute__((address_space(3))) void*)l,
      16, 0, 0);
}

// ---- fused f32->bf16 conversion for all 8 tensors ----
struct Cvt8 { const float* in[8]; short* out[8]; };
__global__ __launch_bounds__(256) void cvt8_k(Cvt8 a) {
  int b = blockIdx.x, seg, rb;
  if (b < 12288)      { seg = b >> 12;                 rb = b & 4095; }
  else if (b < 16384) { seg = 3 + ((b - 12288) >> 10); rb = (b - 12288) & 1023; }
  else                { seg = 7;                       rb = b - 16384; }
  int i = rb * 256 + threadIdx.x;
  float4a v = ((const float4a*)a.in[seg])[i];
  short4v o;
  o.x = f2bf(v.x); o.y = f2bf(v.y); o.z = f2bf(v.z); o.w = f2bf(v.w);
  ((short4v*)a.out[seg])[i] = o;
}

// ---- tiled GEMM, BK=64 rows (128 B = all 32 banks) + XOR swizzle ----
// Fused Q/K/V projections; 128x128 tile; 2x2 waves of 64x64.
// Q output is pre-scaled by (1/sqrt(128))*log2(e) so attention can use exp2.
__global__ __launch_bounds__(256) void gemm_qkv(
    const short* __restrict__ Qb, const short* __restrict__ Kb, const short* __restrict__ Vb,
    const short* __restrict__ Wq, const short* __restrict__ Wk, const short* __restrict__ Wv,
    short* __restrict__ Qp, short* __restrict__ Kp, short* __restrict__ Vt) {
  __shared__ short pool[16384];        // As=pool[0:8192), Bs=pool[8192:16384)
  short* As = pool;
  short* Bs = pool + 8192;
  int seg = blockIdx.x >> 8, bid = blockIdx.x & 255;
  const short* A = seg == 0 ? Qb : (seg == 1 ? Kb : Vb);
  const short* W = seg == 0 ? Wq : (seg == 1 ? Wk : Wv);
  int mt = bid >> 3, nt = bid & 7;
  int m0 = mt * 128, n0 = nt * 128;
  int tid = threadIdx.x;
  int lane = tid & 63, wid = tid >> 6;
  int l15 = lane & 15, quad = lane >> 4;
  int wm = wid & 1, wn = wid >> 1;

  int srow = lane >> 3, sunit = (lane & 7) ^ (lane >> 3);
  const short* gA = A + (m0 + wid * 32 + srow) * 1024 + sunit * 8;
  const short* gB = W + (n0 + wid * 32 + srow) * 1024 + sunit * 8;
  short* lA = As + (wid * 32) * 64;
  short* lB = Bs + (wid * 32) * 64;
  int sw = l15 & 7;

  float4a acc[4][4];
#pragma unroll
  for (int i = 0; i < 4; ++i)
#pragma unroll
    for (int j = 0; j < 4; ++j) acc[i][j] = (float4a){0, 0, 0, 0};

  for (int kc = 0; kc < 1024; kc += 64) {
    __syncthreads();
#pragma unroll
    for (int t = 0; t < 4; ++t) {
      gl2lds(gA + kc + t * 8192, lA + t * 512);
      gl2lds(gB + kc + t * 8192, lB + t * 512);
    }
    __syncthreads();
#pragma unroll
    for (int ks = 0; ks < 2; ++ks) {
      short8 af[4], bfr[4];
#pragma unroll
      for (int i = 0; i < 4; ++i)
        af[i] = *(const short8*)&As[(wm * 64 + i * 16 + l15) * 64 +
                                    (((ks * 4 + quad) ^ sw) * 8)];
#pragma unroll
      for (int j = 0; j < 4; ++j)
        bfr[j] = *(const short8*)&Bs[(wn * 64 + j * 16 + l15) * 64 +
                                     (((ks * 4 + quad) ^ sw) * 8)];
#pragma unroll
      for (int i = 0; i < 4; ++i)
#pragma unroll
        for (int j = 0; j < 4; ++j) acc[i][j] = MFMA16(af[i], bfr[j], acc[i][j]);
    }
  }

  if (seg < 2) {
    // Qp/Kp: n = h*128+d, d consecutive across lanes -> direct stores
    float scl = (seg == 0) ? 0.12752745707470575f : 1.0f;  // sc * log2(e) for Q
#pragma unroll
    for (int i = 0; i < 4; ++i)
#pragma unroll
      for (int j = 0; j < 4; ++j)
#pragma unroll
        for (int r = 0; r < 4; ++r) {
          int m = m0 + wm * 64 + i * 16 + quad * 4 + r;
          int n = n0 + wn * 64 + j * 16 + l15;
          int bb = m >> 10, s = m & 1023, hh = n >> 7, d = n & 127;
          short v = f2bf(acc[i][j][r] * scl);
          if (seg == 0) Qp[(((bb * 8 + hh) * 1024) + s) * 128 + d] = v;
          else          Kp[(((bb * 8 + hh) * 1024) + s) * 128 + d] = v;
        }
  } else {
    // Vt: transpose through LDS, then coalesced 256B-row stores.
    short* T = pool;                   // 64 x 132 shorts
    int b2 = m0 >> 10, s0 = m0 & 1023;
    long vb2 = (long)(b2 * 8 + nt) * 131072;
#pragma unroll
    for (int hd = 0; hd < 2; ++hd) {
      __syncthreads();
      if (wn == hd) {
#pragma unroll
        for (int j = 0; j < 4; ++j)
#pragma unroll
          for (int i = 0; i < 4; ++i)
#pragma unroll
            for (int r = 0; r < 4; ++r)
              T[(j * 16 + l15) * 132 + wm * 64 + i * 16 + quad * 4 + r] =
                  f2bf(acc[i][j][r]);
      }
      __syncthreads();
#pragma unroll
      for (int rr = 0; rr < 4; ++rr) {
        int d = rr * 16 + (tid >> 4);
        short8 v = *(const short8*)&T[d * 132 + (tid & 15) * 8];
        *(short8*)&Vt[vb2 + (hd * 64 + d) * 1024 + s0 + (tid & 15) * 8] = v;
      }
    }
  }
}

// ---- output projection: out(f32) = O2 @ Wo^T. 128x64 tiles, BK=64 swizzled. ----
__global__ __launch_bounds__(256) void gemm_o(const short* __restrict__ A,
                                              const short* __restrict__ W,
                                              float* __restrict__ C) {
  __shared__ short As[128 * 64];
  __shared__ short Bs[64 * 64];
  int bid = blockIdx.x;
  int mt = bid >> 4, nt = bid & 15;
  int m0 = mt * 128, n0 = nt * 64;
  int lane = threadIdx.x & 63, wid = threadIdx.x >> 6;
  int l15 = lane & 15, quad = lane >> 4;
  int wm = wid & 1, wn = wid >> 1;

  int srow = lane >> 3, sunit = (lane & 7) ^ (lane >> 3);
  const short* gA = A + (m0 + wid * 32 + srow) * 1024 + sunit * 8;
  const short* gB = W + (n0 + wid * 16 + srow) * 1024 + sunit * 8;
  short* lA = As + (wid * 32) * 64;
  short* lB = Bs + (wid * 16) * 64;
  int sw = l15 & 7;

  float4a acc[4][2];
#pragma unroll
  for (int i = 0; i < 4; ++i)
#pragma unroll
    for (int j = 0; j < 2; ++j) acc[i][j] = (float4a){0, 0, 0, 0};

  for (int kc = 0; kc < 1024; kc += 64) {
    __syncthreads();
#pragma unroll
    for (int t = 0; t < 4; ++t) gl2lds(gA + kc + t * 8192, lA + t * 512);
#pragma unroll
    for (int t = 0; t < 2; ++t) gl2lds(gB + kc + t * 8192, lB + t * 512);
    __syncthreads();
#pragma unroll
    for (int ks = 0; ks < 2; ++ks) {
      short8 af[4], bfr[2];
#pragma unroll
      for (int i = 0; i < 4; ++i)
        af[i] = *(const short8*)&As[(wm * 64 + i * 16 + l15) * 64 +
                                    (((ks * 4 + quad) ^ sw) * 8)];
#pragma unroll
      for (int j = 0; j < 2; ++j)
        bfr[j] = *(const short8*)&Bs[(wn * 32 + j * 16 + l15) * 64 +
                                     (((ks * 4 + quad) ^ sw) * 8)];
#pragma unroll
      for (int i = 0; i < 4; ++i)
#pragma unroll
        for (int j = 0; j < 2; ++j) acc[i][j] = MFMA16(af[i], bfr[j], acc[i][j]);
    }
  }

#pragma unroll
  for (int i = 0; i < 4; ++i)
#pragma unroll
    for (int j = 0; j < 2; ++j)
#pragma unroll
      for (int r = 0; r < 4; ++r) {
        int m = m0 + wm * 64 + i * 16 + quad * 4 + r;
        int n = n0 + wn * 32 + j * 16 + l15;
        C[m * 1024 + n] = acc[i][j][r];
      }
}

// Qrel[bh, q, r] = sum_d Qp[bh,q,d] * rel[h,r,d]   (bf16 out, 258-padded rows)
__global__ __launch_bounds__(256) void qrel_k(const short* __restrict__ Qp,
                                              const short* __restrict__ rel,
                                              short* __restrict__ Qrel) {
  int lane = threadIdx.x & 63, wid = threadIdx.x >> 6;
  int gw = blockIdx.x * 4 + wid;
  int bh = gw / 1088;
  int rem = gw - bh * 1088;
  int mt = rem / 17;
  int nt = rem - mt * 17;
  int l15 = lane & 15, quad = lane >> 4;
  int h = bh & 7;

  const short* arow = Qp + bh * 131072 + (mt * 16 + l15) * 128 + quad * 8;
  int col = nt * 16 + l15;
  int colc = col > 256 ? 256 : col;
  const short* brow = rel + (h * 257 + colc) * 128 + quad * 8;

  float4a acc = {0, 0, 0, 0};
#pragma unroll
  for (int kc = 0; kc < 128; kc += 32) {
    short8 a = *(const short8*)(arow + kc);
    short8 b = *(const short8*)(brow + kc);
    acc = MFMA16(a, b, acc);
  }
  if (col < 257) {
#pragma unroll
    for (int r = 0; r < 4; ++r) {
      int q = mt * 16 + quad * 4 + r;
      Qrel[bh * 264192 + q * 258 + col] = f2bf(acc[r]);
    }
  }
}

// Banded attention v4: 32-query blocks, 4 band-quarter waves, swapped QK^T
// (P lane-local per q-row), cvt_pk+permlane32_swap in-register P->A fragments,
// XCD-grouped bh so each XCD's L2 retains its K/V, exp2-folded scaling.
__global__ __launch_bounds__(256, 3) void attn_k(const short* __restrict__ Qp,
                                                 const short* __restrict__ Kp,
                                                 const short* __restrict__ Vt,
                                                 const short* __restrict__ Qrel,
                                                 const unsigned char* __restrict__ kpm,
                                                 short* __restrict__ O2) {
  __shared__ __align__(16) short qlds[32 * 258];   // 16512 B, 258-stride rows
  __shared__ float obuf[32][128];                  // 16384 B
  __shared__ float lbuf[32];
  int tid = threadIdx.x;
  int lane = tid & 63, wid = tid >> 6;             // wid = band quarter
  int bid = blockIdx.x;
  // XCD-grouping: 32 q-blocks of a bh all land on one XCD (bid%8 fixed per bh)
  int bh = ((bid & 7) << 2) | ((bid >> 3) & 3);
  int qsb = bid >> 5;
  int q0 = qsb * 32;
  int l31 = lane & 31, hl = lane >> 5;
  int b = bh >> 3, h = bh & 7;

  {
    float* ob = &obuf[0][0];
#pragma unroll
    for (int i = 0; i < 16; ++i) ob[tid + i * 256] = 0.f;
    if (tid < 32) lbuf[tid] = 0.f;
  }
  {
    const unsigned long long* src =
        (const unsigned long long*)(Qrel + bh * 264192 + q0 * 258);
    unsigned long long* dst = (unsigned long long*)qlds;
    for (int i = tid; i < 2064; i += 256) dst[i] = src[i];
  }

  short8 aq[8];
  const short* qrow = Qp + bh * 131072 + (q0 + l31) * 128 + hl * 8;
#pragma unroll
  for (int s = 0; s < 8; ++s) aq[s] = *(const short8*)(qrow + s * 16);
  __syncthreads();

  float16a O[4];
#pragma unroll
  for (int d = 0; d < 4; ++d)
#pragma unroll
    for (int i = 0; i < 16; ++i) O[d][i] = 0.f;
  float lsum = 0.f;

  int klo = q0 - 256; if (klo < 0) klo = 0;        // 32-aligned
  int khi = q0 + 288; if (khi > 1024) khi = 1024;

  const short* kbase = Kp + bh * 131072 + hl * 8;
  const short* vbase = Vt + bh * 131072 + hl * 8;
  const unsigned char* pmrow = kpm + b * 1024;
  int qv = q0 + l31;                // this lane's q-row
  int rowb = l31 * 258;

  int k0 = klo + wid * 32;
  short8 kb[8];
  unsigned pm32 = 0;
  if (k0 < khi) {
    const short* krow = kbase + (k0 + l31) * 128;
#pragma unroll
    for (int s = 0; s < 8; ++s) kb[s] = *(const short8*)(krow + s * 16);
    pm32 = (unsigned)__ballot(pmrow[k0 + l31] != 0);
  }

  for (; k0 < khi; k0 += 128) {
    unsigned pmc = pm32;
    // S = K^T-as-A x Q-as-B : C col(lane)=q, row(reg,hl)=key offset
    float16a S;
#pragma unroll
    for (int i = 0; i < 16; ++i) S[i] = 0.f;
#pragma unroll
    for (int s = 0; s < 8; ++s) S = MFMA32(kb[s], aq[s], S);

    // V fragments (B-operand: lane = d)
    short8 vb0[4], vb1[4];
#pragma unroll
    for (int dblk = 0; dblk < 4; ++dblk) {
      const short* vrow = vbase + (dblk * 32 + l31) * 1024 + k0;
      vb0[dblk] = *(const short8*)(vrow);
      vb1[dblk] = *(const short8*)(vrow + 16);
    }

    // softmax epilogue: per-lane q-row, 16 key-offsets in regs
    int dq = k0 - qv;
    bool edge = (k0 - q0 < -224) | (k0 - q0 > 224) | (pmc != 0);
    if (!edge) {
      int rb = dq + 4 * hl + 128;
#pragma unroll
      for (int i = 0; i < 16; ++i) {
        int rr = rb + (i & 3) + 8 * (i >> 2);
        rr = rr < 0 ? 0 : (rr > 256 ? 256 : rr);
        float pe = __builtin_amdgcn_exp2f(S[i] + bf2f(qlds[rowb + rr]));
        S[i] = pe;
        lsum += pe;
      }
    } else {
#pragma unroll
      for (int i = 0; i < 16; ++i) {
        int koff = (i & 3) + 8 * (i >> 2) + 4 * hl;
        int dd = dq + koff;
        int rr = dd < -128 ? 0 : (dd > 128 ? 256 : dd + 128);
        float rel = bf2f(qlds[rowb + rr]);
        int msk = (dd < -256) | (dd > 256) | (int)((pmc >> koff) & 1u);
        float pe = msk ? 0.f : __builtin_amdgcn_exp2f(S[i] + rel);
        S[i] = pe;
        lsum += pe;
      }
    }

    // P (f32 C-layout) -> bf16 A-fragments: 8 cvt_pk + 4 permlane32_swap
    short8 ap0, ap1;
    {
      unsigned x0, y0, z0, w0;
      asm("v_cvt_pk_bf16_f32 %0, %1, %2" : "=v"(x0) : "v"(S[0]), "v"(S[1]));
      asm("v_cvt_pk_bf16_f32 %0, %1, %2" : "=v"(y0) : "v"(S[2]), "v"(S[3]));
      asm("v_cvt_pk_bf16_f32 %0, %1, %2" : "=v"(z0) : "v"(S[4]), "v"(S[5]));
      asm("v_cvt_pk_bf16_f32 %0, %1, %2" : "=v"(w0) : "v"(S[6]), "v"(S[7]));
      asm("v_permlane32_swap_b32 %0, %1" : "+v"(x0), "+v"(z0));
      asm("v_permlane32_swap_b32 %0, %1" : "+v"(y0), "+v"(w0));
      uint4v u0 = {x0, y0, z0, w0};
      ap0 = __builtin_bit_cast(short8, u0);
      unsigned x1, y1, z1, w1;
      asm("v_cvt_pk_bf16_f32 %0, %1, %2" : "=v"(x1) : "v"(S[8]), "v"(S[9]));
      asm("v_cvt_pk_bf16_f32 %0, %1, %2" : "=v"(y1) : "v"(S[10]), "v"(S[11]));
      asm("v_cvt_pk_bf16_f32 %0, %1, %2" : "=v"(z1) : "v"(S[12]), "v"(S[13]));
      asm("v_cvt_pk_bf16_f32 %0, %1, %2" : "=v"(w1) : "v"(S[14]), "v"(S[15]));
      asm("v_permlane32_swap_b32 %0, %1" : "+v"(x1), "+v"(z1));
      asm("v_permlane32_swap_b32 %0, %1" : "+v"(y1), "+v"(w1));
      uint4v u1 = {x1, y1, z1, w1};
      ap1 = __builtin_bit_cast(short8, u1);
    }

    // prefetch next K tile + padding bits (hides under PV)
    int kn = k0 + 128;
    if (kn < khi) {
      const short* krow = kbase + (kn + l31) * 128;
#pragma unroll
      for (int s = 0; s < 8; ++s) kb[s] = *(const short8*)(krow + s * 16);
      pm32 = (unsigned)__ballot(pmrow[kn + l31] != 0);
    }

#pragma unroll
    for (int dblk = 0; dblk < 4; ++dblk) {
      O[dblk] = MFMA32(ap0, vb0[dblk], O[dblk]);
      O[dblk] = MFMA32(ap1, vb1[dblk], O[dblk]);
    }
  }

  // combine the 4 band-quarters
  lsum += __shfl_xor(lsum, 32);
  if (hl == 0) atomicAdd(&lbuf[l31], lsum);
#pragma unroll
  for (int dblk = 0; dblk < 4; ++dblk)
#pragma unroll
    for (int i = 0; i < 16; ++i) {
      int qoff = (i & 3) + 8 * (i >> 2) + 4 * hl;
      atomicAdd(&obuf[qoff][dblk * 32 + l31], O[dblk][i]);
    }
  __syncthreads();

#pragma unroll
  for (int i = 0; i < 16; ++i) {
    int idx = tid + i * 256;
    int q = idx >> 7, d = idx & 127;
    float inv = __builtin_amdgcn_rcpf(lbuf[q]);
    O2[(b * 1024 + q0 + q) * 1024 + d * 8 + h] = f2bf(obuf[q][d] * inv);
  }
}

extern "C" void kernel_launch(void* const* d_in, const int* in_sizes, int n_in,
                              void* d_out, int out_size, void* d_ws, size_t ws_size,
                              hipStream_t stream) {
  const float* Q   = (const float*)d_in[0];
  const float* K   = (const float*)d_in[1];
  const float* V   = (const float*)d_in[2];
  const unsigned char* kpm = (const unsigned char*)d_in[4];
  const float* Wq  = (const float*)d_in[5];
  const float* Wk  = (const float*)d_in[6];
  const float* Wv  = (const float*)d_in[7];
  const float* Wo  = (const float*)d_in[8];
  const float* rel = (const float*)d_in[9];
  float* out = (float*)d_out;

  short* ws = (short*)d_ws;
  short* Qb   = ws;
  short* Kb   = Qb + 4194304;
  short* Vb   = Kb + 4194304;
  short* Wqb  = Vb + 4194304;
  short* Wkb  = Wqb + 1048576;
  short* Wvb  = Wkb + 1048576;
  short* Wob  = Wvb + 1048576;
  short* relb = Wob + 1048576;
  short* Qp   = relb + 263168;
  short* Kp   = Qp + 4194304;
  short* Vt   = Kp + 4194304;
  short* O2   = Vt + 4194304;
  // Qrel (32*1024*258 shorts) aliases Qb/Kb/Vb head: those are dead once
  // gemm_qkv has run, and qrel_k/attn_k are stream-ordered after it.
  short* Qrel = Qb;

  Cvt8 ca;
  ca.in[0] = Q;  ca.out[0] = Qb;
  ca.in[1] = K;  ca.out[1] = Kb;
  ca.in[2] = V;  ca.out[2] = Vb;
  ca.in[3] = Wq; ca.out[3] = Wqb;
  ca.in[4] = Wk; ca.out[4] = Wkb;
  ca.in[5] = Wv; ca.out[5] = Wvb;
  ca.in[6] = Wo; ca.out[6] = Wob;
  ca.in[7] = rel; ca.out[7] = relb;
  cvt8_k<<<dim3(16641), dim3(256), 0, stream>>>(ca);

  gemm_qkv<<<dim3(768), dim3(256), 0, stream>>>(Qb, Kb, Vb, Wqb, Wkb, Wvb, Qp, Kp, Vt);
  qrel_k<<<dim3(8704), dim3(256), 0, stream>>>(Qp, relb, Qrel);
  attn_k<<<dim3(1024), dim3(256), 0, stream>>>(Qp, Kp, Vt, Qrel, kpm, O2);
  gemm_o<<<dim3(512), dim3(256), 0, stream>>>(O2, Wob, out);
}